// Round 1
// baseline (281.180 us; speedup 1.0000x reference)
//
#include <hip/hip_runtime.h>

// Problem constants (B=4, S=4096, D=2048, E=8, K=2, cap_factor=1.25)
#define TOKENS      16384
#define DIM         2048
#define D4          512          // DIM / 4 (float4 units)
#define NE          8            // experts
#define CAPACITY    5120         // int(16384*2/8*1.25)
#define NASSIGN     (TOKENS * 2) // 32768 top-k assignments

#define NBLOCKS     512
#define NTHREADS    256
#define WAVES_PER_BLOCK 4
#define TOTAL_WAVES (NBLOCKS * WAVES_PER_BLOCK)   // 2048; each wave: 2 tokens/iter

// d_out layout (all float32, tuple order):
//   [0, 32768)        expert_indices as float  [B,S,K]
//   [32768, 65536)    expert_weights           [B,S,K]
//   [65536]           load_balance_loss
//   [65537, 98305)    expert_mask              [B,S,K]

__device__ __forceinline__ void process_token(
    const float (&z)[NE], int t,
    float (&imp_acc)[NE], int (&cnt_acc)[NE],
    float* __restrict__ out_idx, float* __restrict__ out_w)
{
    // softmax over 8 (for importance accumulation)
    float m = z[0];
#pragma unroll
    for (int e = 1; e < NE; e++) m = fmaxf(m, z[e]);
    float pe[NE], s = 0.f;
#pragma unroll
    for (int e = 0; e < NE; e++) { pe[e] = expf(z[e] - m); s += pe[e]; }
    float inv = 1.f / s;
#pragma unroll
    for (int e = 0; e < NE; e++) imp_acc[e] += pe[e] * inv;

    // top-2 on logits (softmax is monotone); ties -> lowest index (jax top_k)
    int i1 = 0; float v1 = z[0];
#pragma unroll
    for (int e = 1; e < NE; e++) { if (z[e] > v1) { v1 = z[e]; i1 = e; } }
    int i2 = -1; float v2 = -3.4e38f;
#pragma unroll
    for (int e = 0; e < NE; e++) { if (e != i1 && z[e] > v2) { v2 = z[e]; i2 = e; } }

    // renormalized top-2 weights: p1/(p1+p2) = 1/(1+exp(z2-z1))  (no dynamic reg idx)
    float w1 = 1.f / (1.f + expf(v2 - v1));
    float w2 = 1.f - w1;

#pragma unroll
    for (int e = 0; e < NE; e++) cnt_acc[e] += (e == i1) + (e == i2);

    out_idx[2 * t]     = (float)i1;
    out_idx[2 * t + 1] = (float)i2;
    out_w[2 * t]       = w1;
    out_w[2 * t + 1]   = w2;
}

__global__ __launch_bounds__(NTHREADS, 2) void router_main(
    const float* __restrict__ x, const float* __restrict__ wg,
    float* __restrict__ out_idx, float* __restrict__ out_w,
    float* __restrict__ imp_g, int* __restrict__ cnt_g)
{
    __shared__ float4 wlds[NE * D4];     // 64 KiB
    __shared__ float  imp_lds[NE];
    __shared__ int    cnt_lds[NE];

    const int tid = threadIdx.x;
    if (tid < NE) { imp_lds[tid] = 0.f; cnt_lds[tid] = 0; }

    const float4* wg4 = (const float4*)wg;
#pragma unroll
    for (int i = tid; i < NE * D4; i += NTHREADS) wlds[i] = wg4[i];
    __syncthreads();

    const int lane  = tid & 63;
    const int wave  = tid >> 6;
    const int gwave = blockIdx.x * WAVES_PER_BLOCK + wave;

    float imp_acc[NE];
    int   cnt_acc[NE];
#pragma unroll
    for (int e = 0; e < NE; e++) { imp_acc[e] = 0.f; cnt_acc[e] = 0; }

    const float4* x4 = (const float4*)x;

    for (int p = gwave; p < TOKENS / 2; p += TOTAL_WAVES) {
        const int t0 = 2 * p, t1 = 2 * p + 1;
        const float4* xr0 = x4 + (size_t)t0 * D4 + lane;
        const float4* xr1 = x4 + (size_t)t1 * D4 + lane;

        // preload both token slices (keeps 16 KB/wave of HBM loads in flight)
        float4 xa[8], xb[8];
#pragma unroll
        for (int j = 0; j < 8; j++) { xa[j] = xr0[j * 64]; xb[j] = xr1[j * 64]; }

        float acc0[NE], acc1[NE];
#pragma unroll
        for (int e = 0; e < NE; e++) { acc0[e] = 0.f; acc1[e] = 0.f; }

#pragma unroll
        for (int j = 0; j < 8; j++) {
#pragma unroll
            for (int e = 0; e < NE; e++) {
                float4 w = wlds[e * D4 + lane + j * 64];
                acc0[e] += xa[j].x * w.x + xa[j].y * w.y + xa[j].z * w.z + xa[j].w * w.w;
                acc1[e] += xb[j].x * w.x + xb[j].y * w.y + xb[j].z * w.z + xb[j].w * w.w;
            }
        }

        // butterfly reduce across the 64 lanes (all lanes end with full sums)
#pragma unroll
        for (int off = 32; off; off >>= 1) {
#pragma unroll
            for (int e = 0; e < NE; e++) {
                acc0[e] += __shfl_xor(acc0[e], off, 64);
                acc1[e] += __shfl_xor(acc1[e], off, 64);
            }
        }

        if (lane == 0) {
            process_token(acc0, t0, imp_acc, cnt_acc, out_idx, out_w);
            process_token(acc1, t1, imp_acc, cnt_acc, out_idx, out_w);
        }
    }

    // per-block combine, then one global atomic per expert per block
    if (lane == 0) {
#pragma unroll
        for (int e = 0; e < NE; e++) {
            atomicAdd(&imp_lds[e], imp_acc[e]);
            atomicAdd(&cnt_lds[e], cnt_acc[e]);
        }
    }
    __syncthreads();
    if (tid < NE)               atomicAdd(&imp_g[tid], imp_lds[tid]);
    else if (tid < 2 * NE)      atomicAdd(&cnt_g[tid - NE], cnt_lds[tid - NE]);
}

// Capacity mask (exact rank rule, matches lexsort((-wf, idxf)) + rank<capacity)
// plus the load-balance loss scalar.
__global__ void mask_loss_kernel(
    const float* __restrict__ out_idx, const float* __restrict__ out_w,
    float* __restrict__ mask, float* __restrict__ loss_out,
    const float* __restrict__ imp_g, const int* __restrict__ cnt_g)
{
    const int i = blockIdx.x * blockDim.x + threadIdx.x;
    if (i < NASSIGN) {
        const int e = (int)out_idx[i];
        const int c = cnt_g[e];
        float mk = 1.f;
        if (c > CAPACITY) {   // statistically never taken; exact fallback
            const float wi = out_w[i];
            int rank = 0;
            for (int j = 0; j < NASSIGN; j++) {
                if ((int)out_idx[j] == e) {
                    const float wj = out_w[j];
                    if (wj > wi || (wj == wi && j < i)) rank++;
                }
            }
            mk = (rank < CAPACITY) ? 1.f : 0.f;
        }
        mask[i] = mk;
    }
    if (blockIdx.x == 0 && threadIdx.x == 0) {
        float si = 0.f, sc = 0.f, dot = 0.f;
#pragma unroll
        for (int e = 0; e < NE; e++) {
            const float im = imp_g[e];
            const float ct = (float)cnt_g[e];
            si += im; sc += ct; dot += im * ct;
        }
        loss_out[0] = (float)NE * dot / (si * sc);
    }
}

extern "C" void kernel_launch(void* const* d_in, const int* in_sizes, int n_in,
                              void* d_out, int out_size, void* d_ws, size_t ws_size,
                              hipStream_t stream)
{
    const float* x  = (const float*)d_in[0];   // [4,4096,2048] f32
    const float* wg = (const float*)d_in[1];   // [8,2048] f32

    float* out      = (float*)d_out;
    float* out_idx  = out;            // 32768
    float* out_w    = out + 32768;    // 32768
    float* loss     = out + 65536;    // 1
    float* mask     = out + 65537;    // 32768

    float* imp_g = (float*)d_ws;                     // 8 f32
    int*   cnt_g = (int*)((char*)d_ws + 64);         // 8 i32

    hipMemsetAsync(d_ws, 0, 128, stream);

    router_main<<<NBLOCKS, NTHREADS, 0, stream>>>(x, wg, out_idx, out_w, imp_g, cnt_g);
    mask_loss_kernel<<<(NASSIGN + NTHREADS - 1) / NTHREADS, NTHREADS, 0, stream>>>(
        out_idx, out_w, mask, loss, imp_g, cnt_g);
}

// Round 2
// 214.292 us; speedup vs baseline: 1.3121x; 1.3121x over previous
//
#include <hip/hip_runtime.h>

// Problem constants (B=4, S=4096, D=2048, E=8, K=2, cap_factor=1.25)
#define TOKENS      16384
#define DIM         2048
#define D4          512          // DIM / 4 (float4 units)
#define NE          8            // experts
#define CAPACITY    5120         // int(16384*2/8*1.25)
#define NASSIGN     (TOKENS * 2) // 32768 top-k assignments

#define NBLOCKS     512
#define NTHREADS    256
#define WAVES_PER_BLOCK 4
#define TOTAL_WAVES (NBLOCKS * WAVES_PER_BLOCK)   // 2048; each wave: 2 tokens/iter

// d_out layout (all float32, tuple order):
//   [0, 32768)        expert_indices as float  [B,S,K]
//   [32768, 65536)    expert_weights           [B,S,K]
//   [65536]           load_balance_loss
//   [65537, 98305)    expert_mask              [B,S,K]

__device__ __forceinline__ void process_token(
    const float (&z)[NE], int t,
    float (&imp_acc)[NE], int (&cnt_acc)[NE],
    float* __restrict__ out_idx, float* __restrict__ out_w)
{
    // softmax over 8 (for importance accumulation)
    float m = z[0];
#pragma unroll
    for (int e = 1; e < NE; e++) m = fmaxf(m, z[e]);
    float pe[NE], s = 0.f;
#pragma unroll
    for (int e = 0; e < NE; e++) { pe[e] = expf(z[e] - m); s += pe[e]; }
    float inv = 1.f / s;
#pragma unroll
    for (int e = 0; e < NE; e++) imp_acc[e] += pe[e] * inv;

    // top-2 on logits (softmax is monotone); ties -> lowest index (jax top_k)
    int i1 = 0; float v1 = z[0];
#pragma unroll
    for (int e = 1; e < NE; e++) { if (z[e] > v1) { v1 = z[e]; i1 = e; } }
    int i2 = -1; float v2 = -3.4e38f;
#pragma unroll
    for (int e = 0; e < NE; e++) { if (e != i1 && z[e] > v2) { v2 = z[e]; i2 = e; } }

    // renormalized top-2 weights: p1/(p1+p2) = 1/(1+exp(z2-z1))  (no dynamic reg idx)
    float w1 = 1.f / (1.f + expf(v2 - v1));
    float w2 = 1.f - w1;

#pragma unroll
    for (int e = 0; e < NE; e++) cnt_acc[e] += (e == i1) + (e == i2);

    out_idx[2 * t]     = (float)i1;
    out_idx[2 * t + 1] = (float)i2;
    out_w[2 * t]       = w1;
    out_w[2 * t + 1]   = w2;
}

// __launch_bounds__(256) only: min-waves left at 1 so the allocator may use up
// to 512 VGPRs — the (256,2) bound made the 16-float4 x-preload spill to
// scratch (rocprof: WRITE_SIZE 106 MB on a kernel that writes 0.5 MB).
// Occupancy is LDS-capped at 2 blocks/CU regardless (64 KiB w tile).
__global__ __launch_bounds__(NTHREADS) void router_main(
    const float* __restrict__ x, const float* __restrict__ wg,
    float* __restrict__ out_idx, float* __restrict__ out_w,
    float* __restrict__ imp_g, int* __restrict__ cnt_g)
{
    __shared__ float4 wlds[NE * D4];     // 64 KiB
    __shared__ float  imp_lds[NE];
    __shared__ int    cnt_lds[NE];

    const int tid = threadIdx.x;
    if (tid < NE) { imp_lds[tid] = 0.f; cnt_lds[tid] = 0; }

    const float4* wg4 = (const float4*)wg;
#pragma unroll
    for (int i = tid; i < NE * D4; i += NTHREADS) wlds[i] = wg4[i];
    __syncthreads();

    const int lane  = tid & 63;
    const int wave  = tid >> 6;
    const int gwave = blockIdx.x * WAVES_PER_BLOCK + wave;
    const int par   = lane & 1;          // parity for the fold-reduce

    float imp_acc[NE];
    int   cnt_acc[NE];
#pragma unroll
    for (int e = 0; e < NE; e++) { imp_acc[e] = 0.f; cnt_acc[e] = 0; }

    const float4* x4 = (const float4*)x;

    for (int p = gwave; p < TOKENS / 2; p += TOTAL_WAVES) {
        const int t0 = 2 * p;
        const float4* xr0 = x4 + (size_t)t0 * D4 + lane;
        const float4* xr1 = xr0 + D4;

        // 16 dwordx4 loads in flight per wave (16 KB); stays in registers now
        float4 xa[8], xb[8];
#pragma unroll
        for (int j = 0; j < 8; j++) xa[j] = xr0[j * 64];
#pragma unroll
        for (int j = 0; j < 8; j++) xb[j] = xr1[j * 64];

        float acc0[NE], acc1[NE];
#pragma unroll
        for (int e = 0; e < NE; e++) { acc0[e] = 0.f; acc1[e] = 0.f; }

#pragma unroll
        for (int j = 0; j < 8; j++) {
#pragma unroll
            for (int e = 0; e < NE; e++) {
                float4 w = wlds[e * D4 + lane + j * 64];
                acc0[e] += xa[j].x * w.x + xa[j].y * w.y + xa[j].z * w.z + xa[j].w * w.w;
                acc1[e] += xb[j].x * w.x + xb[j].y * w.y + xb[j].z * w.z + xb[j].w * w.w;
            }
        }

        // Fold level (xor 1): even lanes keep token0 sums, odd lanes token1.
        //   send   s = par ? acc0 : acc1   (the token I'm giving away)
        //   keep   k = par ? acc1 : acc0
        float v[NE];
#pragma unroll
        for (int e = 0; e < NE; e++) {
            float snd = par ? acc0[e] : acc1[e];
            float kp  = par ? acc1[e] : acc0[e];
            v[e] = kp + __shfl_xor(snd, 1, 64);
        }
        // Remaining butterfly (masks 2..32) stays within a parity class.
#pragma unroll
        for (int off = 2; off <= 32; off <<= 1) {
#pragma unroll
            for (int e = 0; e < NE; e++) v[e] += __shfl_xor(v[e], off, 64);
        }

        if (lane < 2) {   // lane 0 -> token t0, lane 1 -> token t0+1
            process_token(v, t0 + lane, imp_acc, cnt_acc, out_idx, out_w);
        }
    }

    // per-block combine (lanes 0 and 1 hold accumulators), then global atomics
    if (lane < 2) {
#pragma unroll
        for (int e = 0; e < NE; e++) {
            atomicAdd(&imp_lds[e], imp_acc[e]);
            atomicAdd(&cnt_lds[e], cnt_acc[e]);
        }
    }
    __syncthreads();
    if (tid < NE)               atomicAdd(&imp_g[tid], imp_lds[tid]);
    else if (tid < 2 * NE)      atomicAdd(&cnt_g[tid - NE], cnt_lds[tid - NE]);
}

// Capacity mask (exact rank rule, matches lexsort((-wf, idxf)) + rank<capacity)
// plus the load-balance loss scalar.
__global__ void mask_loss_kernel(
    const float* __restrict__ out_idx, const float* __restrict__ out_w,
    float* __restrict__ mask, float* __restrict__ loss_out,
    const float* __restrict__ imp_g, const int* __restrict__ cnt_g)
{
    const int i = blockIdx.x * blockDim.x + threadIdx.x;
    if (i < NASSIGN) {
        const int e = (int)out_idx[i];
        const int c = cnt_g[e];
        float mk = 1.f;
        if (c > CAPACITY) {   // statistically never taken; exact fallback
            const float wi = out_w[i];
            int rank = 0;
            for (int j = 0; j < NASSIGN; j++) {
                if ((int)out_idx[j] == e) {
                    const float wj = out_w[j];
                    if (wj > wi || (wj == wi && j < i)) rank++;
                }
            }
            mk = (rank < CAPACITY) ? 1.f : 0.f;
        }
        mask[i] = mk;
    }
    if (blockIdx.x == 0 && threadIdx.x == 0) {
        float si = 0.f, sc = 0.f, dot = 0.f;
#pragma unroll
        for (int e = 0; e < NE; e++) {
            const float im = imp_g[e];
            const float ct = (float)cnt_g[e];
            si += im; sc += ct; dot += im * ct;
        }
        loss_out[0] = (float)NE * dot / (si * sc);
    }
}

extern "C" void kernel_launch(void* const* d_in, const int* in_sizes, int n_in,
                              void* d_out, int out_size, void* d_ws, size_t ws_size,
                              hipStream_t stream)
{
    const float* x  = (const float*)d_in[0];   // [4,4096,2048] f32
    const float* wg = (const float*)d_in[1];   // [8,2048] f32

    float* out      = (float*)d_out;
    float* out_idx  = out;            // 32768
    float* out_w    = out + 32768;    // 32768
    float* loss     = out + 65536;    // 1
    float* mask     = out + 65537;    // 32768

    float* imp_g = (float*)d_ws;                     // 8 f32
    int*   cnt_g = (int*)((char*)d_ws + 64);         // 8 i32

    hipMemsetAsync(d_ws, 0, 128, stream);

    router_main<<<NBLOCKS, NTHREADS, 0, stream>>>(x, wg, out_idx, out_w, imp_g, cnt_g);
    mask_loss_kernel<<<(NASSIGN + NTHREADS - 1) / NTHREADS, NTHREADS, 0, stream>>>(
        out_idx, out_w, mask, loss, imp_g, cnt_g);
}

// Round 4
// 199.664 us; speedup vs baseline: 1.4083x; 1.0733x over previous
//
#include <hip/hip_runtime.h>

// Problem constants (B=4, S=4096, D=2048, E=8, K=2, cap_factor=1.25)
#define TOKENS      16384
#define DIM         2048
#define D4          512          // DIM / 4 (float4 units)
#define NE          8            // experts
#define CAPACITY    5120         // int(16384*2/8*1.25)
#define NASSIGN     (TOKENS * 2) // 32768 top-k assignments

#define NBLOCKS     1024
#define NTHREADS    256
#define TOK_PER_WAVE 4           // 1024 blocks * 4 waves * 4 tokens = 16384

// d_out layout (all float32, tuple order):
//   [0, 32768)        expert_indices as float  [B,S,K]
//   [32768, 65536)    expert_weights           [B,S,K]
//   [65536]           load_balance_loss
//   [65537, 98305)    expert_mask              [B,S,K]

// No w-LDS tile: the 64 KiB tile capped us at 2 blocks/CU (Occupancy 21%,
// HBM stuck at ~2.5 TB/s). w is 64 KiB and L2-resident; read it with
// coalesced global float4 loads instead. LDS here is only 64 B of
// block-combine scratch, so occupancy is VGPR-limited (~16 waves/CU).
__global__ __launch_bounds__(NTHREADS) void router_main(
    const float* __restrict__ x, const float* __restrict__ wg,
    float* __restrict__ out_idx, float* __restrict__ out_w,
    float* __restrict__ imp_g, int* __restrict__ cnt_g)
{
    __shared__ float imp_lds[NE];
    __shared__ int   cnt_lds[NE];

    const int tid = threadIdx.x;
    if (tid < NE) { imp_lds[tid] = 0.f; cnt_lds[tid] = 0; }
    __syncthreads();

    const int lane = tid & 63;
    const int wave = tid >> 6;
    const int q    = blockIdx.x * (NTHREADS / 64) + wave;  // wave id 0..4095
    const int tok0 = q * TOK_PER_WAVE;

    const float4* x4  = (const float4*)x;
    const float4* wg4 = (const float4*)wg;
    const float4* xb  = x4 + (size_t)tok0 * D4 + lane;   // + t*D4 + j*64
    const float4* wb  = wg4 + lane;                      // + e*D4 + j*64

    float4 xc[2][TOK_PER_WAVE];   // double-buffered x chunks (32 VGPRs)
    float4 wf[NE];                // current w chunk       (32 VGPRs)
    float  acc[TOK_PER_WAVE][NE]; // partial dots          (32 VGPRs)

#pragma unroll
    for (int t = 0; t < TOK_PER_WAVE; t++)
#pragma unroll
        for (int e = 0; e < NE; e++) acc[t][e] = 0.f;

    // prologue: chunk 0 of x and w
#pragma unroll
    for (int t = 0; t < TOK_PER_WAVE; t++) xc[0][t] = xb[t * D4];
#pragma unroll
    for (int e = 0; e < NE; e++) wf[e] = wb[e * D4];

#pragma unroll
    for (int j = 0; j < 8; j++) {
        const int cur = j & 1, nxt = cur ^ 1;   // compile-time after unroll
        if (j < 7) {
#pragma unroll
            for (int t = 0; t < TOK_PER_WAVE; t++)
                xc[nxt][t] = xb[t * D4 + (j + 1) * 64];
        }
#pragma unroll
        for (int e = 0; e < NE; e++) {
            const float4 w = wf[e];
#pragma unroll
            for (int t = 0; t < TOK_PER_WAVE; t++) {
                acc[t][e] += xc[cur][t].x * w.x + xc[cur][t].y * w.y
                           + xc[cur][t].z * w.z + xc[cur][t].w * w.w;
            }
        }
        if (j < 7) {
#pragma unroll
            for (int e = 0; e < NE; e++) wf[e] = wb[e * D4 + (j + 1) * 64];
        }
    }

    // ---- reduce: fold 4 tokens onto lane&3, then 16-lane-group butterfly ----
    const int p1 = lane & 1, p2 = lane & 2;
    float b0[2][NE], c[NE];
#pragma unroll
    for (int k = 0; k < 2; k++) {
#pragma unroll
        for (int e = 0; e < NE; e++) {
            float snd = p1 ? acc[2 * k][e]     : acc[2 * k + 1][e];
            float kp  = p1 ? acc[2 * k + 1][e] : acc[2 * k][e];
            b0[k][e] = kp + __shfl_xor(snd, 1, 64);
        }
    }
#pragma unroll
    for (int e = 0; e < NE; e++) {
        float snd = p2 ? b0[0][e] : b0[1][e];
        float kp  = p2 ? b0[1][e] : b0[0][e];
        c[e] = kp + __shfl_xor(snd, 2, 64);
    }
#pragma unroll
    for (int off = 4; off <= 32; off <<= 1) {
#pragma unroll
        for (int e = 0; e < NE; e++) c[e] += __shfl_xor(c[e], off, 64);
    }
    // lane l in 0..3 now holds the full 8 logits of token tok0 + l

    if (lane < TOK_PER_WAVE) {
        const int t = tok0 + lane;

        // softmax over 8 (importance)
        float m = c[0];
#pragma unroll
        for (int e = 1; e < NE; e++) m = fmaxf(m, c[e]);
        float pe[NE], s = 0.f;
#pragma unroll
        for (int e = 0; e < NE; e++) { pe[e] = expf(c[e] - m); s += pe[e]; }
        const float inv = 1.f / s;
#pragma unroll
        for (int e = 0; e < NE; e++) atomicAdd(&imp_lds[e], pe[e] * inv);

        // top-2 (ties -> lowest index, jax top_k semantics)
        int i1 = 0; float v1 = c[0];
#pragma unroll
        for (int e = 1; e < NE; e++) { if (c[e] > v1) { v1 = c[e]; i1 = e; } }
        int i2 = -1; float v2 = -3.4e38f;
#pragma unroll
        for (int e = 0; e < NE; e++) { if (e != i1 && c[e] > v2) { v2 = c[e]; i2 = e; } }

        const float w1 = 1.f / (1.f + expf(v2 - v1));   // renormalized pair
        atomicAdd(&cnt_lds[i1], 1);
        atomicAdd(&cnt_lds[i2], 1);

        out_idx[2 * t]     = (float)i1;
        out_idx[2 * t + 1] = (float)i2;
        out_w[2 * t]       = w1;
        out_w[2 * t + 1]   = 1.f - w1;
    }

    __syncthreads();
    if (tid < NE)          atomicAdd(&imp_g[tid], imp_lds[tid]);
    else if (tid < 2 * NE) atomicAdd(&cnt_g[tid - NE], cnt_lds[tid - NE]);
}

// Capacity mask (exact rank rule, matches lexsort((-wf, idxf)) + rank<capacity)
// plus the load-balance loss scalar.
__global__ void mask_loss_kernel(
    const float* __restrict__ out_idx, const float* __restrict__ out_w,
    float* __restrict__ mask, float* __restrict__ loss_out,
    const float* __restrict__ imp_g, const int* __restrict__ cnt_g)
{
    const int i = blockIdx.x * blockDim.x + threadIdx.x;
    if (i < NASSIGN) {
        const int e = (int)out_idx[i];
        const int c = cnt_g[e];
        float mk = 1.f;
        if (c > CAPACITY) {   // statistically never taken; exact fallback
            const float wi = out_w[i];
            int rank = 0;
            for (int j = 0; j < NASSIGN; j++) {
                if ((int)out_idx[j] == e) {
                    const float wj = out_w[j];
                    if (wj > wi || (wj == wi && j < i)) rank++;
                }
            }
            mk = (rank < CAPACITY) ? 1.f : 0.f;
        }
        mask[i] = mk;
    }
    if (blockIdx.x == 0 && threadIdx.x == 0) {
        float si = 0.f, sc = 0.f, dot = 0.f;
#pragma unroll
        for (int e = 0; e < NE; e++) {
            const float im = imp_g[e];
            const float ct = (float)cnt_g[e];
            si += im; sc += ct; dot += im * ct;
        }
        loss_out[0] = (float)NE * dot / (si * sc);
    }
}

extern "C" void kernel_launch(void* const* d_in, const int* in_sizes, int n_in,
                              void* d_out, int out_size, void* d_ws, size_t ws_size,
                              hipStream_t stream)
{
    const float* x  = (const float*)d_in[0];   // [4,4096,2048] f32
    const float* wg = (const float*)d_in[1];   // [8,2048] f32

    float* out      = (float*)d_out;
    float* out_idx  = out;            // 32768
    float* out_w    = out + 32768;    // 32768
    float* loss     = out + 65536;    // 1
    float* mask     = out + 65537;    // 32768

    float* imp_g = (float*)d_ws;                     // 8 f32
    int*   cnt_g = (int*)((char*)d_ws + 64);         // 8 i32

    hipMemsetAsync(d_ws, 0, 128, stream);

    router_main<<<NBLOCKS, NTHREADS, 0, stream>>>(x, wg, out_idx, out_w, imp_g, cnt_g);
    mask_loss_kernel<<<(NASSIGN + NTHREADS - 1) / NTHREADS, NTHREADS, 0, stream>>>(
        out_idx, out_w, mask, loss, imp_g, cnt_g);
}